// Round 15
// baseline (1471.167 us; speedup 1.0000x reference)
//
#include <hip/hip_runtime.h>
#include <hip/hip_bf16.h>

#define BS_   4096
#define NQ_   21
#define NK_   7
#define E_    512
#define MQ_   (BS_*NQ_)   // 86016 q rows
#define MK_   (BS_*NK_)   // 28672 k rows
#define KT_   (MK_/128)   // 224 k tiles (flags 0..223, produced FIRST)
#define QT_   (MQ_/128)   // 672 q tiles (flags 224..895)
#define NPROD_ 3584
#define NCONS_ 1024
#define SCALE_ 2.88539008177792681f   // 2*log2(e): exp2(SCALE*x) = e^{2x}

typedef __attribute__((ext_vector_type(8))) short bf16x8;
typedef __attribute__((ext_vector_type(4))) float f32x4;
typedef __attribute__((ext_vector_type(8))) unsigned short u16x8;

__device__ __forceinline__ unsigned int cvt_pk_bf16(float lo, float hi){
  unsigned int r;
  asm("v_cvt_pk_bf16_f32 %0, %1, %2" : "=v"(r) : "v"(lo), "v"(hi));
  return r;
}
__device__ __forceinline__ float bf2f(unsigned short h){
  return __builtin_bit_cast(float, (unsigned int)h << 16);
}
__device__ __forceinline__ void gload_lds16(const void* g, void* l){
  __builtin_amdgcn_global_load_lds(
      (const __attribute__((address_space(1))) unsigned int*)g,
      (__attribute__((address_space(3))) unsigned int*)l, 16, 0, 0);
}

// ---------------- weight cast f32 -> bf16 ----------------
__global__ __launch_bounds__(256) void cast_weights(
    const float* __restrict__ wq, const float* __restrict__ wk,
    unsigned int* __restrict__ oq, unsigned int* __restrict__ ok)
{
  int i = blockIdx.x * 256 + threadIdx.x;           // 65536 float4s each
  float4 a = ((const float4*)wq)[i];
  float4 b = ((const float4*)wk)[i];
  uint2 ua = { cvt_pk_bf16(a.x, a.y), cvt_pk_bf16(a.z, a.w) };
  uint2 ub = { cvt_pk_bf16(b.x, b.y), cvt_pk_bf16(b.z, b.w) };
  ((uint2*)oq)[i] = ua;
  ((uint2*)ok)[i] = ub;
}

// ---------------- attn per-wave body (one batch per wave) -------------------
// q''/k'' bf16 pre-scaled by 2*log2(e).
// score = Wsum - 2*sum_h wv_h/(1+e^{2(q+k)}); raw keys RELOADED per q-row
// (L1-resident 14KB/batch) to keep VGPR < 128 for 4-blocks/CU co-residency.
__device__ __forceinline__ void attn_wave(long b, int lane,
    const unsigned short* qp, const unsigned short* kp, const float* keys,
    const float* wv, const float* wvb, const int* mask,
    float* out0, float* out1)
{
  float wvr[8];
  *(float4*)&wvr[0] = ((const float4*)wv)[lane * 2];
  *(float4*)&wvr[4] = ((const float4*)wv)[lane * 2 + 1];

  float kf[NK_][8];
#pragma unroll
  for (int k = 0; k < NK_; ++k){
    u16x8 u = *(const u16x8*)(kp + (b * NK_ + k) * E_ + lane * 8);
#pragma unroll
    for (int j = 0; j < 8; ++j) kf[k][j] = bf2f((unsigned short)u[j]);
  }

  float wsum = ((wvr[0] + wvr[1]) + (wvr[2] + wvr[3])) + ((wvr[4] + wvr[5]) + (wvr[6] + wvr[7]));
#pragma unroll
  for (int off = 32; off; off >>= 1) wsum += __shfl_xor(wsum, off, 64);

  const float vb = wvb[0];
  float base[NK_];
#pragma unroll
  for (int k = 0; k < NK_; ++k)
    base[k] = (wsum + vb) + (float)mask[b * NK_ + k] * (-1e9f);   // fp32 absorption == ref

  const unsigned short* qrow = qp + b * NQ_ * E_ + lane * 8;
  const float* krow = keys + b * NK_ * E_ + lane * 8;
  u16x8 qv = *(const u16x8*)qrow;

  float4* o0 = (float4*)(out0 + b * NQ_ * E_) + lane * 2;
  float*  o1 = out1 + b * (NQ_ * NK_);

  for (int qi = 0; qi < NQ_; ++qi){
    u16x8 qn = qv;
    if (qi < NQ_ - 1) qn = *(const u16x8*)(qrow + (qi + 1) * E_);
    float qf[8];
#pragma unroll
    for (int j = 0; j < 8; ++j) qf[j] = bf2f((unsigned short)qv[j]);
    qv = qn;

    float acs[NK_];
#pragma unroll
    for (int k = 0; k < NK_; ++k){
      float a = 0.f;
#pragma unroll
      for (int j = 0; j < 8; ++j){
        float x = qf[j] + kf[k][j];
        float e = __builtin_amdgcn_exp2f(x);
        float r = __builtin_amdgcn_rcpf(e + 1.0f);
        a = fmaf(wvr[j], r, a);
      }
      acs[k] = a;
    }
#pragma unroll
    for (int k = 0; k < NK_; ++k){
      float a = acs[k];
#pragma unroll
      for (int off = 32; off; off >>= 1) a += __shfl_xor(a, off, 64);
      acs[k] = a;
    }
    float sc[NK_], mx = -3.4e38f;
#pragma unroll
    for (int k = 0; k < NK_; ++k){ sc[k] = fmaf(-2.f, acs[k], base[k]); mx = fmaxf(mx, sc[k]); }
    float sum = 0.f;
#pragma unroll
    for (int k = 0; k < NK_; ++k){ sc[k] = __expf(sc[k] - mx); sum += sc[k]; }
    const float inv = __builtin_amdgcn_rcpf(sum);
    float wgt[NK_];
#pragma unroll
    for (int k = 0; k < NK_; ++k) wgt[k] = sc[k] * inv;

    float wsel = wgt[0];
#pragma unroll
    for (int k = 1; k < NK_; ++k) wsel = (lane == k) ? wgt[k] : wsel;
    if (lane < NK_) o1[qi * NK_ + lane] = wsel;

    float4 lo = {0.f,0.f,0.f,0.f}, hi = {0.f,0.f,0.f,0.f};
#pragma unroll
    for (int k = 0; k < NK_; ++k){
      const float4 p0 = *(const float4*)(krow + k * E_);
      const float4 p1 = *(const float4*)(krow + k * E_ + 4);
      lo.x = fmaf(wgt[k], p0.x, lo.x);  lo.y = fmaf(wgt[k], p0.y, lo.y);
      lo.z = fmaf(wgt[k], p0.z, lo.z);  lo.w = fmaf(wgt[k], p0.w, lo.w);
      hi.x = fmaf(wgt[k], p1.x, hi.x);  hi.y = fmaf(wgt[k], p1.y, hi.y);
      hi.z = fmaf(wgt[k], p1.z, hi.z);  hi.w = fmaf(wgt[k], p1.w, hi.w);
    }
    o0[qi * 128 + 0] = lo;
    o0[qi * 128 + 1] = hi;
  }
}

// ---------------- producer-consumer fused kernel ----------------------------
// Blocks: 1024 producers, then 512 groups of {5 producers, 2 consumers}.
// Producer = r9's proven gemm (all-bf16 LDS, 0 conflicts), k-tiles first,
// publishes per-tile flags (threadfence + device atomicAdd, 4 = complete).
// Consumer = bounded spin (acquire/agent) on <=4 flags -> attn (4 batches,
// one/wave) or mark pending for the sweep kernel. Bounded spin => no deadlock
// under ANY dispatch order; sweep guarantees completion.
__global__ __launch_bounds__(256, 4)
void fused_pc(const float* Aq, const float* Ak,
              const unsigned short* Bq, const unsigned short* Bk,
              const float* bq, const float* bk,
              unsigned short* Cq, unsigned short* Ck,
              const float* keys, const float* wv, const float* wvb,
              const int* mask, float* out0, float* out1,
              int* flags, int* pending)
{
  __shared__ char SH[32768];
  __shared__ int okflag;
  const int tid = threadIdx.x;

  int pid = -1, cid = -1;
  {
    const int bx = (int)blockIdx.x;
    if (bx < 1024) pid = bx;
    else {
      const int r = bx - 1024, grp = r / 7, off = r % 7;
      if (off < 5) pid = 1024 + grp * 5 + off;
      else         cid = grp * 2 + (off - 5);
    }
  }

  if (pid >= 0){
    // ================= producer: r9 gemm body =================
    const int lane = tid & 63;
    const int w    = tid >> 6;
    const int wr   = w >> 1, wc = w & 1;

    const int orig = pid;
    const int j    = orig >> 3;
    const int mtl  = (j >> 2) * 8 + (orig & 7);   // 0..895, k tiles first
    const int nt   = j & 3;

    const float* A; const unsigned short* Bw; const float* bias; unsigned short* C;
    int mt;
    if (mtl < KT_){ A = Ak; Bw = Bk; bias = bk; C = Ck; mt = mtl; }
    else          { A = Aq; Bw = Bq; bias = bq; C = Cq; mt = mtl - KT_; }

    const long m0 = (long)mt << 7;
    const int  n0 = nt << 7;
    const char* Abyte = (const char*)(A + m0 * E_);
    const char* Bbyte = (const char*)Bw;

#define ASMB(B) (SH + (B) * 8192)
#define BSMB(B) (SH + 16384 + (B) * 8192)

    long asrc[4]; int adst[4];
#pragma unroll
    for (int i = 0; i < 4; ++i){
      const int c   = tid + i * 256;
      const int row = c >> 3;
      const int sl  = c & 7;
      asrc[i] = (long)row * (E_ * 4) + sl * 16;
      adst[i] = row * 64 + (((sl & 6) * 8) ^ (((row >> 1) & 3) << 4)) + (sl & 1) * 8;
    }
    long bsrc[2]; int bdst[2];
#pragma unroll
    for (int i = 0; i < 2; ++i){
      const int c   = tid + i * 256;
      const int row = c >> 2;
      const int sl  = c & 3;
      bsrc[i] = (long)(n0 + row) * (E_ * 2) + ((sl * 16) ^ (((row >> 1) & 3) << 4));
      bdst[i] = c * 16;
    }
    int aoff[4], boff[4];
#pragma unroll
    for (int m = 0; m < 4; ++m){
      const int r = wr * 64 + m * 16 + (lane & 15);
      aoff[m] = r * 64 + ((16 * (lane >> 4)) ^ (((r >> 1) & 3) << 4));
    }
#pragma unroll
    for (int n = 0; n < 4; ++n){
      const int r = wc * 64 + n * 16 + (lane & 15);
      boff[n] = r * 64 + ((16 * (lane >> 4)) ^ (((r >> 1) & 3) << 4));
    }

    f32x4 acc[4][4];
    const f32x4 z4 = {0.f, 0.f, 0.f, 0.f};
#pragma unroll
    for (int m = 0; m < 4; ++m)
#pragma unroll
      for (int n = 0; n < 4; ++n) acc[m][n] = z4;

    {
      float4 av[4];
#pragma unroll
      for (int i = 0; i < 4; ++i) av[i] = *(const float4*)(Abyte + asrc[i]);
#pragma unroll
      for (int i = 0; i < 2; ++i) gload_lds16(Bbyte + bsrc[i], BSMB(0) + bdst[i]);
#pragma unroll
      for (int i = 0; i < 4; ++i){
        uint2 u = { cvt_pk_bf16(av[i].x, av[i].y), cvt_pk_bf16(av[i].z, av[i].w) };
        *(uint2*)(ASMB(0) + adst[i]) = u;
      }
    }
    __syncthreads();

#pragma unroll 2
    for (int t = 0; t < 16; ++t){
      const int buf = t & 1, nbuf = buf ^ 1;
      float4 av[4];
      if (t < 15){
        const long ka = (long)(t + 1) * 128;
        const long kb2 = (long)(t + 1) * 64;
#pragma unroll
        for (int i = 0; i < 4; ++i) av[i] = *(const float4*)(Abyte + asrc[i] + ka);
#pragma unroll
        for (int i = 0; i < 2; ++i) gload_lds16(Bbyte + bsrc[i] + kb2, BSMB(nbuf) + bdst[i]);
      }
      bf16x8 af[4], bfr[4];
#pragma unroll
      for (int m = 0; m < 4; ++m) af[m]  = *(const bf16x8*)(ASMB(buf) + aoff[m]);
#pragma unroll
      for (int n = 0; n < 4; ++n) bfr[n] = *(const bf16x8*)(BSMB(buf) + boff[n]);
#pragma unroll
      for (int m = 0; m < 4; ++m)
#pragma unroll
        for (int n = 0; n < 4; ++n)
          acc[m][n] = __builtin_amdgcn_mfma_f32_16x16x32_bf16(af[m], bfr[n], acc[m][n], 0, 0, 0);
      if (t < 15){
#pragma unroll
        for (int i = 0; i < 4; ++i){
          uint2 u = { cvt_pk_bf16(av[i].x, av[i].y), cvt_pk_bf16(av[i].z, av[i].w) };
          *(uint2*)(ASMB(nbuf) + adst[i]) = u;
        }
      }
      __syncthreads();
    }
#undef ASMB
#undef BSMB

    const int ccol0 = n0 + wc * 64 + (lane & 15);
    float bvs[4];
#pragma unroll
    for (int n = 0; n < 4; ++n) bvs[n] = bias[ccol0 + n * 16] * SCALE_;
#pragma unroll
    for (int m = 0; m < 4; ++m){
      const long rbase = m0 + wr * 64 + m * 16 + (lane >> 4) * 4;
#pragma unroll
      for (int n = 0; n < 4; ++n){
        const long col = ccol0 + n * 16;
        float v0 = fmaf(acc[m][n][0], SCALE_, bvs[n]);
        float v1 = fmaf(acc[m][n][1], SCALE_, bvs[n]);
        float v2 = fmaf(acc[m][n][2], SCALE_, bvs[n]);
        float v3 = fmaf(acc[m][n][3], SCALE_, bvs[n]);
        unsigned int u01 = cvt_pk_bf16(v0, v1);
        unsigned int u23 = cvt_pk_bf16(v2, v3);
        C[(rbase + 0) * E_ + col] = (unsigned short)(u01 & 0xffffu);
        C[(rbase + 1) * E_ + col] = (unsigned short)(u01 >> 16);
        C[(rbase + 2) * E_ + col] = (unsigned short)(u23 & 0xffffu);
        C[(rbase + 3) * E_ + col] = (unsigned short)(u23 >> 16);
      }
    }
    // publish: tile complete when flag reaches 4
    __threadfence();
    __syncthreads();
    if (tid == 0) atomicAdd(&flags[mtl], 1);
    return;
  }

  // ================= consumer: bounded-spin attn =================
  {
    const long B0 = (long)cid * 4;
    if (tid == 0) okflag = 1;
    __syncthreads();

    int f = 0;
    if      (tid == 0) f = (int)((7 * B0) >> 7);
    else if (tid == 1) f = (int)((7 * B0 + 27) >> 7);
    else if (tid == 2) f = KT_ + (int)((21 * B0) >> 7);
    else if (tid == 3) f = KT_ + (int)((21 * B0 + 83) >> 7);
    if (tid < 4){
      int myok = 0;
      for (int it = 0; it < (1 << 18); ++it){
        if (__hip_atomic_load(&flags[f], __ATOMIC_ACQUIRE, __HIP_MEMORY_SCOPE_AGENT) >= 4){
          myok = 1; break;
        }
        __builtin_amdgcn_s_sleep(8);
      }
      if (!myok) atomicAnd(&okflag, 0);
    }
    __syncthreads();
    if (okflag == 0){
      if (tid == 0) pending[cid] = 1;
      return;
    }
    attn_wave(B0 + (tid >> 6), tid & 63,
              (const unsigned short*)Cq, (const unsigned short*)Ck,
              keys, wv, wvb, mask, out0, out1);
    return;
  }
}

// ---------------- sweep: finish any batches the fused kernel skipped --------
__global__ __launch_bounds__(256)
void attn_sweep(const unsigned short* qb, const unsigned short* kb,
                const float* keys, const float* wv, const float* wvb,
                const int* mask, float* out0, float* out1,
                const int* pending)
{
  if (pending[blockIdx.x] == 0) return;   // normal case: immediate exit
  attn_wave((long)blockIdx.x * 4 + (threadIdx.x >> 6), threadIdx.x & 63,
            qb, kb, keys, wv, wvb, mask, out0, out1);
}

// ---------------- launcher ----------------
extern "C" void kernel_launch(void* const* d_in, const int* in_sizes, int n_in,
                              void* d_out, int out_size, void* d_ws, size_t ws_size,
                              hipStream_t stream)
{
  const float* queries = (const float*)d_in[0];
  const float* keys    = (const float*)d_in[1];
  const float* wq_w    = (const float*)d_in[2];
  const float* wq_b    = (const float*)d_in[3];
  const float* wk_w    = (const float*)d_in[4];
  const float* wk_b    = (const float*)d_in[5];
  const float* wv_w    = (const float*)d_in[6];
  const float* wv_b    = (const float*)d_in[7];
  const int*   mask    = (const int*)d_in[8];
  (void)in_sizes; (void)n_in; (void)out_size; (void)ws_size;

  float* out0 = (float*)d_out;
  float* out1 = out0 + (long)MQ_ * E_;

  char* ws = (char*)d_ws;
  unsigned short* wqb     = (unsigned short*)ws;                    // 512 KB
  unsigned short* wkb     = (unsigned short*)(ws + 512 * 1024);     // 512 KB
  int*            flags   = (int*)(ws + (1 << 20));                 // 896 ints
  int*            pending = (int*)(ws + (1 << 20) + 4096);          // 1024 ints
  unsigned short* qb      = (unsigned short*)(ws + (1 << 20) + 8192);
  unsigned short* kb      = qb + (size_t)MQ_ * E_;

  cast_weights<<<dim3(256), dim3(256), 0, stream>>>(wq_w, wk_w, (unsigned int*)wqb, (unsigned int*)wkb);
  hipMemsetAsync(ws + (1 << 20), 0, 8192, stream);
  fused_pc<<<dim3(NPROD_ + NCONS_), dim3(256), 0, stream>>>(
      queries, keys, wqb, wkb, wq_b, wk_b, qb, kb,
      keys, wv_w, wv_b, mask, out0, out1, flags, pending);
  attn_sweep<<<dim3(NCONS_), dim3(256), 0, stream>>>(
      qb, kb, keys, wv_w, wv_b, mask, out0, out1, pending);
}

// Round 16
// 268.120 us; speedup vs baseline: 5.4870x; 5.4870x over previous
//
#include <hip/hip_runtime.h>
#include <hip/hip_bf16.h>

#define BS_   4096
#define NQ_   21
#define NK_   7
#define E_    512
#define MQ_   (BS_*NQ_)   // 86016 q rows
#define MK_   (BS_*NK_)   // 28672 k rows
#define MT1_  (MQ_/128)   // 672 q block-rows
#define MT2_  (MK_/128)   // 224 k block-rows
#define SCALE_ 2.88539008177792681f   // 2*log2(e): exp2(SCALE*x) = e^{2x}

typedef __attribute__((ext_vector_type(8))) short bf16x8;
typedef __attribute__((ext_vector_type(4))) float f32x4;
typedef __attribute__((ext_vector_type(8))) unsigned short u16x8;

__device__ __forceinline__ unsigned int cvt_pk_bf16(float lo, float hi){
  unsigned int r;
  asm("v_cvt_pk_bf16_f32 %0, %1, %2" : "=v"(r) : "v"(lo), "v"(hi));
  return r;
}
__device__ __forceinline__ float bf2f(unsigned short h){
  return __builtin_bit_cast(float, (unsigned int)h << 16);
}
__device__ __forceinline__ void gload_lds16(const void* g, void* l){
  __builtin_amdgcn_global_load_lds(
      (const __attribute__((address_space(1))) unsigned int*)g,
      (__attribute__((address_space(3))) unsigned int*)l, 16, 0, 0);
}

// ---------------- weight cast f32 -> bf16 ----------------
__global__ __launch_bounds__(256) void cast_weights(
    const float* __restrict__ wq, const float* __restrict__ wk,
    unsigned int* __restrict__ oq, unsigned int* __restrict__ ok)
{
  int i = blockIdx.x * 256 + threadIdx.x;           // 65536 float4s each
  float4 a = ((const float4*)wq)[i];
  float4 b = ((const float4*)wk)[i];
  uint2 ua = { cvt_pk_bf16(a.x, a.y), cvt_pk_bf16(a.z, a.w) };
  uint2 ub = { cvt_pk_bf16(b.x, b.y), cvt_pk_bf16(b.z, b.w) };
  ((uint2*)oq)[i] = ua;
  ((uint2*)ok)[i] = ub;
}

// ---------------- merged projection GEMMs, counted-vmcnt pipeline -----------
// (r10 body, verbatim — best measured GEMM: 156 us, 0 bank conflicts)
__global__ __launch_bounds__(256)
void gemm_proj(const float* __restrict__ Aq, const float* __restrict__ Ak,
               const unsigned short* __restrict__ Bq, const unsigned short* __restrict__ Bk,
               const float* __restrict__ bq, const float* __restrict__ bk,
               unsigned short* __restrict__ Cq, unsigned short* __restrict__ Ck)
{
  __shared__ char Asm[3][128 * 64];   // 8 KB each: bf16 A-tile
  __shared__ char Bsm[3][128 * 64];   // 8 KB each: bf16 B-tile

  const int tid  = threadIdx.x;
  const int lane = tid & 63;
  const int w    = tid >> 6;
  const int wr   = w >> 1, wc = w & 1;

  // XCD-grouped bijection (3584 blocks % 8 == 0): nt fastest per XCD.
  const int orig = (int)blockIdx.x;
  const int j    = orig >> 3;
  int       mt   = (j >> 2) * 8 + (orig & 7);
  const int nt   = j & 3;

  const float* A; const unsigned short* Bw; const float* bias; unsigned short* C;
  if (mt < MT1_){ A = Aq; Bw = Bq; bias = bq; C = Cq; }
  else          { A = Ak; Bw = Bk; bias = bk; C = Ck; mt -= MT1_; }

  const long m0 = (long)mt << 7;
  const int  n0 = nt << 7;
  const char* Abyte = (const char*)(A + m0 * E_);
  const char* Bbyte = (const char*)Bw;

  long asrc[4]; int adst[4];
#pragma unroll
  for (int i = 0; i < 4; ++i){
    const int c   = tid + i * 256;
    const int row = c >> 3;
    const int sl  = c & 7;
    asrc[i] = (long)row * (E_ * 4) + sl * 16;
    adst[i] = row * 64 + (((sl & 6) * 8) ^ (((row >> 1) & 3) << 4)) + (sl & 1) * 8;
  }
  long bsrc[2]; int bdst[2];
#pragma unroll
  for (int i = 0; i < 2; ++i){
    const int c   = tid + i * 256;
    const int row = c >> 2;
    const int sl  = c & 3;
    bsrc[i] = (long)(n0 + row) * (E_ * 2) + ((sl * 16) ^ (((row >> 1) & 3) << 4));
    bdst[i] = c * 16;
  }

  int aoff[4], boff[4];
#pragma unroll
  for (int m = 0; m < 4; ++m){
    const int r = wr * 64 + m * 16 + (lane & 15);
    aoff[m] = r * 64 + ((16 * (lane >> 4)) ^ (((r >> 1) & 3) << 4));
  }
#pragma unroll
  for (int n = 0; n < 4; ++n){
    const int r = wc * 64 + n * 16 + (lane & 15);
    boff[n] = r * 64 + ((16 * (lane >> 4)) ^ (((r >> 1) & 3) << 4));
  }

  f32x4 acc[4][4];
  const f32x4 z4 = {0.f, 0.f, 0.f, 0.f};
#pragma unroll
  for (int m = 0; m < 4; ++m)
#pragma unroll
    for (int n = 0; n < 4; ++n) acc[m][n] = z4;

#define STAGE_LOADS(av, T) do { \
  _Pragma("unroll") for (int i_ = 0; i_ < 4; ++i_) \
    av[i_] = *(const float4*)(Abyte + asrc[i_] + (long)(T) * 128); \
} while(0)

#define STAGE_B(BUF, T) do { \
  _Pragma("unroll") for (int i_ = 0; i_ < 2; ++i_) \
    gload_lds16(Bbyte + bsrc[i_] + (long)(T) * 64, Bsm[BUF] + bdst[i_]); \
} while(0)

#define WRITE_A(BUF, av) do { \
  _Pragma("unroll") for (int i_ = 0; i_ < 4; ++i_){ \
    uint2 u_ = { cvt_pk_bf16(av[i_].x, av[i_].y), cvt_pk_bf16(av[i_].z, av[i_].w) }; \
    *(uint2*)(Asm[BUF] + adst[i_]) = u_; \
  } \
} while(0)

#define COMPUTE(BUF) do { \
  bf16x8 af_[4], bfr_[4]; \
  _Pragma("unroll") for (int m_ = 0; m_ < 4; ++m_) af_[m_]  = *(const bf16x8*)(Asm[BUF] + aoff[m_]); \
  _Pragma("unroll") for (int n_ = 0; n_ < 4; ++n_) bfr_[n_] = *(const bf16x8*)(Bsm[BUF] + boff[n_]); \
  _Pragma("unroll") for (int m_ = 0; m_ < 4; ++m_) \
    _Pragma("unroll") for (int n_ = 0; n_ < 4; ++n_) \
      acc[m_][n_] = __builtin_amdgcn_mfma_f32_16x16x32_bf16(af_[m_], bfr_[n_], acc[m_][n_], 0, 0, 0); \
} while(0)

#define BARRIER() do { \
  asm volatile("" ::: "memory"); \
  __builtin_amdgcn_s_barrier(); \
  asm volatile("" ::: "memory"); \
} while(0)

  float4 avA[4], avB[4];

  STAGE_LOADS(avA, 0);  STAGE_B(0, 0);
  STAGE_LOADS(avB, 1);  STAGE_B(1, 1);
  asm volatile("s_waitcnt vmcnt(6)" ::: "memory");
  WRITE_A(0, avA);

#pragma unroll
  for (int t = 0; t < 14; ++t){
    const int cur = t % 3, nx1 = (t + 1) % 3, nx2 = (t + 2) % 3;
    (void)cur;
    asm volatile("s_waitcnt vmcnt(2)" ::: "memory");
    if ((t & 1) == 0) WRITE_A(nx1, avB); else WRITE_A(nx1, avA);
    asm volatile("s_waitcnt lgkmcnt(0)" ::: "memory");
    BARRIER();
    if ((t & 1) == 0) STAGE_LOADS(avA, t + 2); else STAGE_LOADS(avB, t + 2);
    STAGE_B(nx2, t + 2);
    COMPUTE(t % 3);
  }
  {
    asm volatile("s_waitcnt vmcnt(2)" ::: "memory");
    WRITE_A(0, avB);
    asm volatile("s_waitcnt lgkmcnt(0)" ::: "memory");
    BARRIER();
    COMPUTE(2);
  }
  {
    asm volatile("s_waitcnt vmcnt(0)" ::: "memory");
    BARRIER();
    COMPUTE(0);
  }

#undef STAGE_LOADS
#undef STAGE_B
#undef WRITE_A
#undef COMPUTE
#undef BARRIER

  const int ccol0 = n0 + wc * 64 + (lane & 15);
  float bvs[4];
#pragma unroll
  for (int n = 0; n < 4; ++n) bvs[n] = bias[ccol0 + n * 16] * SCALE_;
#pragma unroll
  for (int m = 0; m < 4; ++m){
    const long rbase = m0 + wr * 64 + m * 16 + (lane >> 4) * 4;
#pragma unroll
    for (int n = 0; n < 4; ++n){
      const long col = ccol0 + n * 16;
      float v0 = fmaf(acc[m][n][0], SCALE_, bvs[n]);
      float v1 = fmaf(acc[m][n][1], SCALE_, bvs[n]);
      float v2 = fmaf(acc[m][n][2], SCALE_, bvs[n]);
      float v3 = fmaf(acc[m][n][3], SCALE_, bvs[n]);
      unsigned int u01 = cvt_pk_bf16(v0, v1);
      unsigned int u23 = cvt_pk_bf16(v2, v3);
      C[(rbase + 0) * E_ + col] = (unsigned short)(u01 & 0xffffu);
      C[(rbase + 1) * E_ + col] = (unsigned short)(u01 >> 16);
      C[(rbase + 2) * E_ + col] = (unsigned short)(u23 & 0xffffu);
      C[(rbase + 3) * E_ + col] = (unsigned short)(u23 >> 16);
    }
  }
}

// ---------------- fused score + softmax + weighted sum ----------------
// TWO waves per batch (q rows 0-10 / 11-20); q''/k'' bf16 pre-scaled by
// 2*log2(e). Factored exponential: e^{2(q+k)} = EQ*EK with EQ=exp2(q''),
// EK=exp2(k'') precomputed -> hot loop per element is fma+rcp+fma
// (1 trans + 2 full-rate, was 2 trans + 3 full).
// score = Wsum - 2*sum_h wv_h/(1 + EQ_h*EK_h)
__global__ __launch_bounds__(256, 2)
void attn_fused(const unsigned short* __restrict__ qp,
                const unsigned short* __restrict__ kp,
                const float* __restrict__ keys,
                const float* __restrict__ wv, const float* __restrict__ wvb,
                const int* __restrict__ mask,
                float* __restrict__ out0, float* __restrict__ out1)
{
  const int lane = threadIdx.x & 63;
  const int w    = threadIdx.x >> 6;                 // 0..3
  const long b   = (long)blockIdx.x * 2 + (w >> 1);  // 2 batches per block
  const int  q0  = (w & 1) * 11;                     // 0 or 11
  const int  q1  = (w & 1) ? NQ_ : 11;

  // per-lane wv slice (h = lane*8 .. +7)
  float wvr[8];
  *(float4*)&wvr[0] = ((const float4*)wv)[lane * 2];
  *(float4*)&wvr[4] = ((const float4*)wv)[lane * 2 + 1];

  // EK = exp2(k'') -> f32 regs [7][8]
  float ek[NK_][8];
#pragma unroll
  for (int k = 0; k < NK_; ++k){
    u16x8 u = *(const u16x8*)(kp + (b * NK_ + k) * E_ + lane * 8);
#pragma unroll
    for (int j = 0; j < 8; ++j)
      ek[k][j] = __builtin_amdgcn_exp2f(bf2f((unsigned short)u[j]));
  }
  // raw keys -> f32 regs [7][8]
  float kr[NK_][8];
#pragma unroll
  for (int k = 0; k < NK_; ++k){
    const float4* p = (const float4*)(keys + (b * NK_ + k) * E_ + lane * 8);
    *(float4*)&kr[k][0] = p[0];
    *(float4*)&kr[k][4] = p[1];
  }

  // Wsum = sum_h wv_h (butterfly over lanes)
  float wsum = ((wvr[0] + wvr[1]) + (wvr[2] + wvr[3])) + ((wvr[4] + wvr[5]) + (wvr[6] + wvr[7]));
#pragma unroll
  for (int off = 32; off; off >>= 1) wsum += __shfl_xor(wsum, off, 64);

  const float vb = wvb[0];
  float base[NK_];
#pragma unroll
  for (int k = 0; k < NK_; ++k)
    base[k] = (wsum + vb) + (float)mask[b * NK_ + k] * (-1e9f);   // fp32 absorption == ref

  const unsigned short* qrow = qp + b * NQ_ * E_ + lane * 8;
  u16x8 qv = *(const u16x8*)(qrow + q0 * E_);

  float4* o0 = (float4*)(out0 + b * NQ_ * E_) + lane * 2;
  float*  o1 = out1 + b * (NQ_ * NK_);

  for (int qi = q0; qi < q1; ++qi){
    // prefetch next q row (hides HBM latency under this iteration's compute)
    u16x8 qn = qv;
    if (qi < q1 - 1) qn = *(const u16x8*)(qrow + (qi + 1) * E_);

    float eq[8];
#pragma unroll
    for (int j = 0; j < 8; ++j)
      eq[j] = __builtin_amdgcn_exp2f(bf2f((unsigned short)qv[j]));
    qv = qn;

    // hot loop: 7 independent accumulator chains, 1 trans + 2 full per elem
    float acc[NK_];
#pragma unroll
    for (int k = 0; k < NK_; ++k){
      float a = 0.f;
#pragma unroll
      for (int j = 0; j < 8; ++j){
        float t = fmaf(eq[j], ek[k][j], 1.0f);       // 1 + e^{2(q+k)}
        float r = __builtin_amdgcn_rcpf(t);          // sigmoid(-2(q+k))
        a = fmaf(wvr[j], r, a);
      }
      acc[k] = a;
    }
    // 7 independent butterflies (chains pipeline)
#pragma unroll
    for (int k = 0; k < NK_; ++k){
      float a = acc[k];
#pragma unroll
      for (int off = 32; off; off >>= 1) a += __shfl_xor(a, off, 64);
      acc[k] = a;
    }
    // scores + 7-wide softmax (all lanes redundantly, registers only)
    float sc[NK_], mx = -3.4e38f;
#pragma unroll
    for (int k = 0; k < NK_; ++k){ sc[k] = fmaf(-2.f, acc[k], base[k]); mx = fmaxf(mx, sc[k]); }
    float sum = 0.f;
#pragma unroll
    for (int k = 0; k < NK_; ++k){ sc[k] = __expf(sc[k] - mx); sum += sc[k]; }
    const float inv = __builtin_amdgcn_rcpf(sum);
    float wgt[NK_];
#pragma unroll
    for (int k = 0; k < NK_; ++k) wgt[k] = sc[k] * inv;

    // attn_weights: lanes 0..6 write wgt[lane] (branchless select)
    float wsel = wgt[0];
#pragma unroll
    for (int k = 1; k < NK_; ++k) wsel = (lane == k) ? wgt[k] : wsel;
    if (lane < NK_) o1[qi * NK_ + lane] = wsel;

    // attn_out = weights @ raw keys (all in registers)
    float4 lo = {0.f,0.f,0.f,0.f}, hi = {0.f,0.f,0.f,0.f};
#pragma unroll
    for (int k = 0; k < NK_; ++k){
      lo.x = fmaf(wgt[k], kr[k][0], lo.x);
      lo.y = fmaf(wgt[k], kr[k][1], lo.y);
      lo.z = fmaf(wgt[k], kr[k][2], lo.z);
      lo.w = fmaf(wgt[k], kr[k][3], lo.w);
      hi.x = fmaf(wgt[k], kr[k][4], hi.x);
      hi.y = fmaf(wgt[k], kr[k][5], hi.y);
      hi.z = fmaf(wgt[k], kr[k][6], hi.z);
      hi.w = fmaf(wgt[k], kr[k][7], hi.w);
    }
    o0[qi * 128 + 0] = lo;
    o0[qi * 128 + 1] = hi;
  }
}

// ---------------- launcher ----------------
extern "C" void kernel_launch(void* const* d_in, const int* in_sizes, int n_in,
                              void* d_out, int out_size, void* d_ws, size_t ws_size,
                              hipStream_t stream)
{
  const float* queries = (const float*)d_in[0];
  const float* keys    = (const float*)d_in[1];
  const float* wq_w    = (const float*)d_in[2];
  const float* wq_b    = (const float*)d_in[3];
  const float* wk_w    = (const float*)d_in[4];
  const float* wk_b    = (const float*)d_in[5];
  const float* wv_w    = (const float*)d_in[6];
  const float* wv_b    = (const float*)d_in[7];
  const int*   mask    = (const int*)d_in[8];
  (void)in_sizes; (void)n_in; (void)out_size; (void)ws_size;

  float* out0 = (float*)d_out;
  float* out1 = out0 + (long)MQ_ * E_;

  char* ws = (char*)d_ws;
  unsigned short* wqb = (unsigned short*)ws;                       // 512 KB
  unsigned short* wkb = (unsigned short*)(ws + 512 * 512 * 2);     // 512 KB
  unsigned short* qb  = (unsigned short*)(ws + (1 << 20));         // 88.1 MB
  unsigned short* kb  = qb + (size_t)MQ_ * E_;                     // 29.4 MB

  cast_weights<<<dim3(256), dim3(256), 0, stream>>>(wq_w, wk_w, (unsigned int*)wqb, (unsigned int*)wkb);
  gemm_proj<<<dim3((MT1_ + MT2_) * 4), dim3(256), 0, stream>>>(
      queries, keys, wqb, wkb, wq_b, wk_b, qb, kb);
  attn_fused<<<dim3(BS_ / 2), dim3(256), 0, stream>>>(qb, kb, keys, wv_w, wv_b, mask, out0, out1);
}

// Round 17
// 244.132 us; speedup vs baseline: 6.0261x; 1.0983x over previous
//
#include <hip/hip_runtime.h>
#include <hip/hip_bf16.h>

#define BS_   4096
#define NQ_   21
#define NK_   7
#define E_    512
#define MQ_   (BS_*NQ_)   // 86016 q rows
#define MK_   (BS_*NK_)   // 28672 k rows
#define MT1_  (MQ_/128)   // 672 q block-rows
#define MT2_  (MK_/128)   // 224 k block-rows
#define SCALE_ 2.88539008177792681f   // 2*log2(e): exp2(SCALE*x) = e^{2x}

typedef __attribute__((ext_vector_type(8))) short bf16x8;
typedef __attribute__((ext_vector_type(4))) float f32x4;
typedef __attribute__((ext_vector_type(8))) unsigned short u16x8;

__device__ __forceinline__ unsigned int cvt_pk_bf16(float lo, float hi){
  unsigned int r;
  asm("v_cvt_pk_bf16_f32 %0, %1, %2" : "=v"(r) : "v"(lo), "v"(hi));
  return r;
}
__device__ __forceinline__ float bf2f(unsigned short h){
  return __builtin_bit_cast(float, (unsigned int)h << 16);
}
__device__ __forceinline__ void gload_lds16(const void* g, void* l){
  __builtin_amdgcn_global_load_lds(
      (const __attribute__((address_space(1))) unsigned int*)g,
      (__attribute__((address_space(3))) unsigned int*)l, 16, 0, 0);
}

// ---------------- weight cast f32 -> bf16 ----------------
__global__ __launch_bounds__(256) void cast_weights(
    const float* __restrict__ wq, const float* __restrict__ wk,
    unsigned int* __restrict__ oq, unsigned int* __restrict__ ok)
{
  int i = blockIdx.x * 256 + threadIdx.x;           // 65536 float4s each
  float4 a = ((const float4*)wq)[i];
  float4 b = ((const float4*)wk)[i];
  uint2 ua = { cvt_pk_bf16(a.x, a.y), cvt_pk_bf16(a.z, a.w) };
  uint2 ub = { cvt_pk_bf16(b.x, b.y), cvt_pk_bf16(b.z, b.w) };
  ((uint2*)oq)[i] = ua;
  ((uint2*)ok)[i] = ub;
}

// ---------------- merged projection GEMMs, counted-vmcnt pipeline -----------
// (r10 body, verbatim — best measured GEMM: ~155 us, 0 bank conflicts)
__global__ __launch_bounds__(256)
void gemm_proj(const float* __restrict__ Aq, const float* __restrict__ Ak,
               const unsigned short* __restrict__ Bq, const unsigned short* __restrict__ Bk,
               const float* __restrict__ bq, const float* __restrict__ bk,
               unsigned short* __restrict__ Cq, unsigned short* __restrict__ Ck)
{
  __shared__ char Asm[3][128 * 64];   // 8 KB each: bf16 A-tile
  __shared__ char Bsm[3][128 * 64];   // 8 KB each: bf16 B-tile

  const int tid  = threadIdx.x;
  const int lane = tid & 63;
  const int w    = tid >> 6;
  const int wr   = w >> 1, wc = w & 1;

  // XCD-grouped bijection (3584 blocks % 8 == 0): nt fastest per XCD.
  const int orig = (int)blockIdx.x;
  const int j    = orig >> 3;
  int       mt   = (j >> 2) * 8 + (orig & 7);
  const int nt   = j & 3;

  const float* A; const unsigned short* Bw; const float* bias; unsigned short* C;
  if (mt < MT1_){ A = Aq; Bw = Bq; bias = bq; C = Cq; }
  else          { A = Ak; Bw = Bk; bias = bk; C = Ck; mt -= MT1_; }

  const long m0 = (long)mt << 7;
  const int  n0 = nt << 7;
  const char* Abyte = (const char*)(A + m0 * E_);
  const char* Bbyte = (const char*)Bw;

  long asrc[4]; int adst[4];
#pragma unroll
  for (int i = 0; i < 4; ++i){
    const int c   = tid + i * 256;
    const int row = c >> 3;
    const int sl  = c & 7;
    asrc[i] = (long)row * (E_ * 4) + sl * 16;
    adst[i] = row * 64 + (((sl & 6) * 8) ^ (((row >> 1) & 3) << 4)) + (sl & 1) * 8;
  }
  long bsrc[2]; int bdst[2];
#pragma unroll
  for (int i = 0; i < 2; ++i){
    const int c   = tid + i * 256;
    const int row = c >> 2;
    const int sl  = c & 3;
    bsrc[i] = (long)(n0 + row) * (E_ * 2) + ((sl * 16) ^ (((row >> 1) & 3) << 4));
    bdst[i] = c * 16;
  }

  int aoff[4], boff[4];
#pragma unroll
  for (int m = 0; m < 4; ++m){
    const int r = wr * 64 + m * 16 + (lane & 15);
    aoff[m] = r * 64 + ((16 * (lane >> 4)) ^ (((r >> 1) & 3) << 4));
  }
#pragma unroll
  for (int n = 0; n < 4; ++n){
    const int r = wc * 64 + n * 16 + (lane & 15);
    boff[n] = r * 64 + ((16 * (lane >> 4)) ^ (((r >> 1) & 3) << 4));
  }

  f32x4 acc[4][4];
  const f32x4 z4 = {0.f, 0.f, 0.f, 0.f};
#pragma unroll
  for (int m = 0; m < 4; ++m)
#pragma unroll
    for (int n = 0; n < 4; ++n) acc[m][n] = z4;

#define STAGE_LOADS(av, T) do { \
  _Pragma("unroll") for (int i_ = 0; i_ < 4; ++i_) \
    av[i_] = *(const float4*)(Abyte + asrc[i_] + (long)(T) * 128); \
} while(0)

#define STAGE_B(BUF, T) do { \
  _Pragma("unroll") for (int i_ = 0; i_ < 2; ++i_) \
    gload_lds16(Bbyte + bsrc[i_] + (long)(T) * 64, Bsm[BUF] + bdst[i_]); \
} while(0)

#define WRITE_A(BUF, av) do { \
  _Pragma("unroll") for (int i_ = 0; i_ < 4; ++i_){ \
    uint2 u_ = { cvt_pk_bf16(av[i_].x, av[i_].y), cvt_pk_bf16(av[i_].z, av[i_].w) }; \
    *(uint2*)(Asm[BUF] + adst[i_]) = u_; \
  } \
} while(0)

#define COMPUTE(BUF) do { \
  bf16x8 af_[4], bfr_[4]; \
  _Pragma("unroll") for (int m_ = 0; m_ < 4; ++m_) af_[m_]  = *(const bf16x8*)(Asm[BUF] + aoff[m_]); \
  _Pragma("unroll") for (int n_ = 0; n_ < 4; ++n_) bfr_[n_] = *(const bf16x8*)(Bsm[BUF] + boff[n_]); \
  _Pragma("unroll") for (int m_ = 0; m_ < 4; ++m_) \
    _Pragma("unroll") for (int n_ = 0; n_ < 4; ++n_) \
      acc[m_][n_] = __builtin_amdgcn_mfma_f32_16x16x32_bf16(af_[m_], bfr_[n_], acc[m_][n_], 0, 0, 0); \
} while(0)

#define BARRIER() do { \
  asm volatile("" ::: "memory"); \
  __builtin_amdgcn_s_barrier(); \
  asm volatile("" ::: "memory"); \
} while(0)

  float4 avA[4], avB[4];

  STAGE_LOADS(avA, 0);  STAGE_B(0, 0);
  STAGE_LOADS(avB, 1);  STAGE_B(1, 1);
  asm volatile("s_waitcnt vmcnt(6)" ::: "memory");
  WRITE_A(0, avA);

#pragma unroll
  for (int t = 0; t < 14; ++t){
    const int nx1 = (t + 1) % 3, nx2 = (t + 2) % 3;
    asm volatile("s_waitcnt vmcnt(2)" ::: "memory");
    if ((t & 1) == 0) WRITE_A(nx1, avB); else WRITE_A(nx1, avA);
    asm volatile("s_waitcnt lgkmcnt(0)" ::: "memory");
    BARRIER();
    if ((t & 1) == 0) STAGE_LOADS(avA, t + 2); else STAGE_LOADS(avB, t + 2);
    STAGE_B(nx2, t + 2);
    COMPUTE(t % 3);
  }
  {
    asm volatile("s_waitcnt vmcnt(2)" ::: "memory");
    WRITE_A(0, avB);
    asm volatile("s_waitcnt lgkmcnt(0)" ::: "memory");
    BARRIER();
    COMPUTE(2);
  }
  {
    asm volatile("s_waitcnt vmcnt(0)" ::: "memory");
    BARRIER();
    COMPUTE(0);
  }

#undef STAGE_LOADS
#undef STAGE_B
#undef WRITE_A
#undef COMPUTE
#undef BARRIER

  const int ccol0 = n0 + wc * 64 + (lane & 15);
  float bvs[4];
#pragma unroll
  for (int n = 0; n < 4; ++n) bvs[n] = bias[ccol0 + n * 16] * SCALE_;
#pragma unroll
  for (int m = 0; m < 4; ++m){
    const long rbase = m0 + wr * 64 + m * 16 + (lane >> 4) * 4;
#pragma unroll
    for (int n = 0; n < 4; ++n){
      const long col = ccol0 + n * 16;
      float v0 = fmaf(acc[m][n][0], SCALE_, bvs[n]);
      float v1 = fmaf(acc[m][n][1], SCALE_, bvs[n]);
      float v2 = fmaf(acc[m][n][2], SCALE_, bvs[n]);
      float v3 = fmaf(acc[m][n][3], SCALE_, bvs[n]);
      unsigned int u01 = cvt_pk_bf16(v0, v1);
      unsigned int u23 = cvt_pk_bf16(v2, v3);
      C[(rbase + 0) * E_ + col] = (unsigned short)(u01 & 0xffffu);
      C[(rbase + 1) * E_ + col] = (unsigned short)(u01 >> 16);
      C[(rbase + 2) * E_ + col] = (unsigned short)(u23 & 0xffffu);
      C[(rbase + 3) * E_ + col] = (unsigned short)(u23 >> 16);
    }
  }
}

// ---------------- fused score + softmax + weighted sum ----------------
// ONE wave per batch (r10's proven structure: constant 0..21 q-loop, fully
// unrollable -> consecutive rows' hot loops hide butterfly/softmax latency).
// Single change vs r10: factored exponential e^{2(q+k)} = EQ*EK with
// EK=exp2(k'') hoisted to setup; hot loop = fma+rcp+fma (1 trans + 2 full,
// was 2 trans + 3 full).  score = Wsum - 2*sum_h wv_h/(1 + EQ_h*EK_h)
__global__ __launch_bounds__(256, 2)
void attn_fused(const unsigned short* __restrict__ qp,
                const unsigned short* __restrict__ kp,
                const float* __restrict__ keys,
                const float* __restrict__ wv, const float* __restrict__ wvb,
                const int* __restrict__ mask,
                float* __restrict__ out0, float* __restrict__ out1)
{
  const int lane = threadIdx.x & 63;
  const long b   = (long)blockIdx.x * 4 + (threadIdx.x >> 6);

  // per-lane wv slice (h = lane*8 .. +7)
  float wvr[8];
  *(float4*)&wvr[0] = ((const float4*)wv)[lane * 2];
  *(float4*)&wvr[4] = ((const float4*)wv)[lane * 2 + 1];

  // EK = exp2(k'') -> f32 regs [7][8]
  float ek[NK_][8];
#pragma unroll
  for (int k = 0; k < NK_; ++k){
    u16x8 u = *(const u16x8*)(kp + (b * NK_ + k) * E_ + lane * 8);
#pragma unroll
    for (int j = 0; j < 8; ++j)
      ek[k][j] = __builtin_amdgcn_exp2f(bf2f((unsigned short)u[j]));
  }
  // raw keys -> f32 regs [7][8]
  float kr[NK_][8];
#pragma unroll
  for (int k = 0; k < NK_; ++k){
    const float4* p = (const float4*)(keys + (b * NK_ + k) * E_ + lane * 8);
    *(float4*)&kr[k][0] = p[0];
    *(float4*)&kr[k][4] = p[1];
  }

  // Wsum = sum_h wv_h (butterfly over lanes)
  float wsum = ((wvr[0] + wvr[1]) + (wvr[2] + wvr[3])) + ((wvr[4] + wvr[5]) + (wvr[6] + wvr[7]));
#pragma unroll
  for (int off = 32; off; off >>= 1) wsum += __shfl_xor(wsum, off, 64);

  const float vb = wvb[0];
  float base[NK_];
#pragma unroll
  for (int k = 0; k < NK_; ++k)
    base[k] = (wsum + vb) + (float)mask[b * NK_ + k] * (-1e9f);   // fp32 absorption == ref

  const unsigned short* qrow = qp + b * NQ_ * E_ + lane * 8;
  u16x8 qv = *(const u16x8*)qrow;

  float4* o0 = (float4*)(out0 + b * NQ_ * E_) + lane * 2;
  float*  o1 = out1 + b * (NQ_ * NK_);

  for (int qi = 0; qi < NQ_; ++qi){
    // prefetch next q row (hides HBM latency under this iteration's compute)
    u16x8 qn = qv;
    if (qi < NQ_ - 1) qn = *(const u16x8*)(qrow + (qi + 1) * E_);

    float eq[8];
#pragma unroll
    for (int j = 0; j < 8; ++j)
      eq[j] = __builtin_amdgcn_exp2f(bf2f((unsigned short)qv[j]));
    qv = qn;

    // hot loop: 7 independent accumulator chains, fma+rcp+fma per element
    float acc[NK_];
#pragma unroll
    for (int k = 0; k < NK_; ++k){
      float a = 0.f;
#pragma unroll
      for (int j = 0; j < 8; ++j){
        float t = fmaf(eq[j], ek[k][j], 1.0f);       // 1 + e^{2(q+k)}
        float r = __builtin_amdgcn_rcpf(t);          // sigmoid(-2(q+k))
        a = fmaf(wvr[j], r, a);
      }
      acc[k] = a;
    }
    // 7 independent butterflies (chains pipeline)
#pragma unroll
    for (int k = 0; k < NK_; ++k){
      float a = acc[k];
#pragma unroll
      for (int off = 32; off; off >>= 1) a += __shfl_xor(a, off, 64);
      acc[k] = a;
    }
    // scores + 7-wide softmax (all lanes redundantly, registers only)
    float sc[NK_], mx = -3.4e38f;
#pragma unroll
    for (int k = 0; k < NK_; ++k){ sc[k] = fmaf(-2.f, acc[k], base[k]); mx = fmaxf(mx, sc[k]); }
    float sum = 0.f;
#pragma unroll
    for (int k = 0; k < NK_; ++k){ sc[k] = __expf(sc[k] - mx); sum += sc[k]; }
    const float inv = __builtin_amdgcn_rcpf(sum);
    float wgt[NK_];
#pragma unroll
    for (int k = 0; k < NK_; ++k) wgt[k] = sc[k] * inv;

    // attn_weights: lanes 0..6 write wgt[lane] (branchless select)
    float wsel = wgt[0];
#pragma unroll
    for (int k = 1; k < NK_; ++k) wsel = (lane == k) ? wgt[k] : wsel;
    if (lane < NK_) o1[qi * NK_ + lane] = wsel;

    // attn_out = weights @ raw keys (all in registers)
    float4 lo = {0.f,0.f,0.f,0.f}, hi = {0.f,0.f,0.f,0.f};
#pragma unroll
    for (int k = 0; k < NK_; ++k){
      lo.x = fmaf(wgt[k], kr[k][0], lo.x);
      lo.y = fmaf(wgt[k], kr[k][1], lo.y);
      lo.z = fmaf(wgt[k], kr[k][2], lo.z);
      lo.w = fmaf(wgt[k], kr[k][3], lo.w);
      hi.x = fmaf(wgt[k], kr[k][4], hi.x);
      hi.y = fmaf(wgt[k], kr[k][5], hi.y);
      hi.z = fmaf(wgt[k], kr[k][6], hi.z);
      hi.w = fmaf(wgt[k], kr[k][7], hi.w);
    }
    o0[qi * 128 + 0] = lo;
    o0[qi * 128 + 1] = hi;
  }
}

// ---------------- launcher ----------------
extern "C" void kernel_launch(void* const* d_in, const int* in_sizes, int n_in,
                              void* d_out, int out_size, void* d_ws, size_t ws_size,
                              hipStream_t stream)
{
  const float* queries = (const float*)d_in[0];
  const float* keys    = (const float*)d_in[1];
  const float* wq_w    = (const float*)d_in[2];
  const float* wq_b    = (const float*)d_in[3];
  const float* wk_w    = (const float*)d_in[4];
  const float* wk_b    = (const float*)d_in[5];
  const float* wv_w    = (const float*)d_in[6];
  const float* wv_b    = (const float*)d_in[7];
  const int*   mask    = (const int*)d_in[8];
  (void)in_sizes; (void)n_in; (void)out_size; (void)ws_size;

  float* out0 = (float*)d_out;
  float* out1 = out0 + (long)MQ_ * E_;

  char* ws = (char*)d_ws;
  unsigned short* wqb = (unsigned short*)ws;                       // 512 KB
  unsigned short* wkb = (unsigned short*)(ws + 512 * 512 * 2);     // 512 KB
  unsigned short* qb  = (unsigned short*)(ws + (1 << 20));         // 88.1 MB
  unsigned short* kb  = qb + (size_t)MQ_ * E_;                     // 29.4 MB

  cast_weights<<<dim3(256), dim3(256), 0, stream>>>(wq_w, wk_w, (unsigned int*)wqb, (unsigned int*)wkb);
  gemm_proj<<<dim3((MT1_ + MT2_) * 4), dim3(256), 0, stream>>>(
      queries, keys, wqb, wkb, wq_b, wk_b, qb, kb);
  attn_fused<<<dim3(BS_ / 4), dim3(256), 0, stream>>>(qb, kb, keys, wv_w, wv_b, mask, out0, out1);
}